// Round 4
// baseline (389.608 us; speedup 1.0000x reference)
//
#include <hip/hip_runtime.h>
#include <float.h>
#include <math.h>

#define B_  8
#define H_  8
#define L_  2048
#define D_  64
#define NS  40          // num selected = min(5*ceil(ln(2048)), 2048) = 40
#define BH  (B_*H_)
#define SCALE 0.125f    // d^-0.5

// ---------------------------------------------------------------------------
// K1: sparsity measure.  One wave per query.  4 lanes x 4 float4 cover one
// k row; 16 groups handle 16 samples per pass; 3 passes cover 40 samples.
// Per pass: 4 gather instrs (16 lines each) + 2 intra-group xor-reduces.
// Final: 4-step cross-group combine.  ~14 DS ops/query vs 52 in R3.
// ---------------------------------------------------------------------------
__global__ __launch_bounds__(256) void measure_kernel(
    const float* __restrict__ q, const float* __restrict__ k,
    const int* __restrict__ ridx, float* __restrict__ measure)
{
    int wave = threadIdx.x >> 6, lane = threadIdx.x & 63;
    int qid = blockIdx.x * 4 + wave;
    int bh  = qid >> 11;                 // / L_
    int i   = qid & (L_ - 1);
    int g   = lane >> 2;                 // group 0..15: one sampled row/pass
    int sl  = lane & 3;                  // sub-lane within group

    const float4* kb = (const float4*)(k + (size_t)bh * L_ * D_);
    const float4* qp = (const float4*)(q + ((size_t)bh * L_ + i) * D_);

    // q fragment: this lane's 4 float4 slices (f4 index it*4+sl)
    float4 q0 = qp[sl], q1 = qp[4 + sl], q2 = qp[8 + sl], q3 = qp[12 + sl];

    float mx = -FLT_MAX, sm = 0.f;
    #pragma unroll
    for (int p = 0; p < 3; ++p) {
        int s = p * 16 + g;
        bool valid = (s < NS);                       // p<2 always valid
        int r = ridx[i * NS + (valid ? s : NS - 1)];
        const float4* kr = kb + (size_t)r * 16;
        float4 k0 = kr[sl], k1 = kr[4 + sl], k2 = kr[8 + sl], k3 = kr[12 + sl];
        float pp = q0.x*k0.x + q0.y*k0.y + q0.z*k0.z + q0.w*k0.w
                 + q1.x*k1.x + q1.y*k1.y + q1.z*k1.z + q1.w*k1.w
                 + q2.x*k2.x + q2.y*k2.y + q2.z*k2.z + q2.w*k2.w
                 + q3.x*k3.x + q3.y*k3.y + q3.z*k3.z + q3.w*k3.w;
        pp += __shfl_xor(pp, 1, 64);
        pp += __shfl_xor(pp, 2, 64);                 // 4 lanes: dot(q, k[r])
        if (valid) { mx = fmaxf(mx, pp); sm += pp; }
    }
    // combine the 16 groups (disjoint samples)
    #pragma unroll
    for (int off = 4; off < 64; off <<= 1) {
        mx = fmaxf(mx, __shfl_xor(mx, off, 64));
        sm += __shfl_xor(sm, off, 64);
    }
    if (lane == 0)
        measure[(size_t)bh * L_ + i] = mx - sm * (1.0f / (float)L_);
}

// ---------------------------------------------------------------------------
// K2: top-NS per (b,h), register-resident.  Ties: lower index (lax.top_k).
// ---------------------------------------------------------------------------
__global__ __launch_bounds__(256) void topk_kernel(
    const float* __restrict__ measure, int* __restrict__ idxOut)
{
    __shared__ float wv[4]; __shared__ int wi[4];
    __shared__ float bvS;   __shared__ int biS;
    int bh = blockIdx.x, t = threadIdx.x;
    const float4* m4 = (const float4*)(measure + (size_t)bh * L_);
    float vals[8];
    float4 a = m4[t*2], b = m4[t*2 + 1];
    vals[0]=a.x; vals[1]=a.y; vals[2]=a.z; vals[3]=a.w;
    vals[4]=b.x; vals[5]=b.y; vals[6]=b.z; vals[7]=b.w;

    float lv = -FLT_MAX; int li = t*8;
    #pragma unroll
    for (int e = 0; e < 8; ++e) if (vals[e] > lv) { lv = vals[e]; li = t*8 + e; }

    int lane = t & 63, w = t >> 6;
    for (int r = 0; r < NS; ++r) {
        float v = lv; int idx = li;
        #pragma unroll
        for (int off = 32; off; off >>= 1) {
            float ov = __shfl_xor(v, off, 64);
            int   oi = __shfl_xor(idx, off, 64);
            if (ov > v || (ov == v && oi < idx)) { v = ov; idx = oi; }
        }
        if (lane == 0) { wv[w] = v; wi[w] = idx; }
        __syncthreads();
        if (t == 0) {
            float bv = wv[0]; int bi = wi[0];
            #pragma unroll
            for (int ww = 1; ww < 4; ++ww)
                if (wv[ww] > bv || (wv[ww] == bv && wi[ww] < bi)) { bv = wv[ww]; bi = wi[ww]; }
            bvS = bv; biS = bi;
            idxOut[bh * NS + r] = bi;
        }
        __syncthreads();
        int bi = biS;
        if ((bi >> 3) == t) {
            #pragma unroll
            for (int e = 0; e < 8; ++e) if ((bi & 7) == e) vals[e] = -FLT_MAX;
            lv = -FLT_MAX; li = t*8;
            #pragma unroll
            for (int e = 0; e < 8; ++e) if (vals[e] > lv) { lv = vals[e]; li = t*8 + e; }
        }
        __syncthreads();
    }
}

// ---------------------------------------------------------------------------
// K3: cumsum(v) along L, two passes, 1024 blocks each.
// ---------------------------------------------------------------------------
__global__ __launch_bounds__(256) void cumsum_p1(
    const float* __restrict__ v, float4* __restrict__ vpart)
{
    __shared__ float4 part[16][16];
    int bh = blockIdx.x >> 4, c = blockIdx.x & 15;
    int d4 = threadIdx.x & 15, sub = threadIdx.x >> 4;
    const float4* vb = (const float4*)(v + (size_t)bh * L_ * D_);
    int r0 = c*128 + sub*8;
    float4 s = make_float4(0,0,0,0);
    #pragma unroll
    for (int r = 0; r < 8; ++r) {
        float4 x = vb[(r0 + r)*16 + d4];
        s.x += x.x; s.y += x.y; s.z += x.z; s.w += x.w;
    }
    part[sub][d4] = s;
    __syncthreads();
    if (sub == 0) {
        float4 tot = part[0][d4];
        #pragma unroll
        for (int ss = 1; ss < 16; ++ss) {
            float4 x = part[ss][d4];
            tot.x += x.x; tot.y += x.y; tot.z += x.z; tot.w += x.w;
        }
        vpart[(bh*16 + c)*16 + d4] = tot;
    }
}

__global__ __launch_bounds__(256) void cumsum_p2(
    const float* __restrict__ v, const float4* __restrict__ vpart,
    float* __restrict__ out)
{
    __shared__ float4 part[16][16];
    int bh = blockIdx.x >> 4, c = blockIdx.x & 15;
    int d4 = threadIdx.x & 15, sub = threadIdx.x >> 4;
    const float4* vb = (const float4*)(v + (size_t)bh * L_ * D_);
    float4*       ob = (float4*)(out + (size_t)bh * L_ * D_);
    int r0 = c*128 + sub*8;
    float4 s = make_float4(0,0,0,0);
    #pragma unroll
    for (int r = 0; r < 8; ++r) {
        float4 x = vb[(r0 + r)*16 + d4];
        s.x += x.x; s.y += x.y; s.z += x.z; s.w += x.w;
    }
    part[sub][d4] = s;
    float4 run = make_float4(0,0,0,0);
    for (int cc = 0; cc < c; ++cc) {
        float4 x = vpart[(bh*16 + cc)*16 + d4];
        run.x += x.x; run.y += x.y; run.z += x.z; run.w += x.w;
    }
    __syncthreads();
    #pragma unroll
    for (int ss = 0; ss < 16; ++ss) {
        if (ss < sub) {
            float4 x = part[ss][d4];
            run.x += x.x; run.y += x.y; run.z += x.z; run.w += x.w;
        }
    }
    #pragma unroll
    for (int r = 0; r < 8; ++r) {
        float4 x = vb[(r0 + r)*16 + d4];
        run.x += x.x; run.y += x.y; run.z += x.z; run.w += x.w;
        ob[(r0 + r)*16 + d4] = run;
    }
}

// ---------------------------------------------------------------------------
// K4a: scores + softmax fused.  Block = (bh, group of 4 ranks), one wave per
// rank.  k staged per 128-row chunk in LDS (transposed f4 +1 pad).  Each
// wave keeps its full 2048-wide score row in 32 registers, does the masked
// softmax wave-locally, writes normalized weights once (zeros past qrow).
// ---------------------------------------------------------------------------
__global__ __launch_bounds__(256) void scores_kernel(
    const float* __restrict__ q, const float* __restrict__ k,
    const int* __restrict__ idxSel, float* __restrict__ attn)
{
    __shared__ float4 kbuf[16 * 129];   // [g][j], stride 129 f4
    int bh = blockIdx.x / 10, grp = blockIdx.x % 10;
    int qi = threadIdx.x >> 6, sub = threadIdx.x & 63;
    int rank = grp*4 + qi;
    int qrow = idxSel[bh*NS + rank];

    const float4* qrp = (const float4*)(q + ((size_t)bh * L_ + qrow) * D_);
    float4 qreg[16];
    #pragma unroll
    for (int g = 0; g < 16; ++g) qreg[g] = qrp[g];    // wave-uniform

    const float4* kb = (const float4*)(k + (size_t)bh * L_ * D_);
    float sc0[16], sc1[16];

    #pragma unroll
    for (int c = 0; c < 16; ++c) {
        __syncthreads();                               // kbuf reuse guard
        int j0 = c * 128;
        #pragma unroll
        for (int it = 0; it < 8; ++it) {               // coalesced stage
            int fi = threadIdx.x + 256*it;
            int g = fi & 15, j = fi >> 4;
            kbuf[g*129 + j] = kb[(size_t)(j0 + j)*16 + g];
        }
        __syncthreads();
        float acc0 = 0.f, acc1 = 0.f;
        #pragma unroll
        for (int g = 0; g < 16; ++g) {
            float4 k0 = kbuf[g*129 + sub];             // dense b128
            float4 k1 = kbuf[g*129 + sub + 64];
            float4 qq = qreg[g];
            acc0 += qq.x*k0.x + qq.y*k0.y + qq.z*k0.z + qq.w*k0.w;
            acc1 += qq.x*k1.x + qq.y*k1.y + qq.z*k1.z + qq.w*k1.w;
        }
        sc0[c] = acc0 * SCALE;
        sc1[c] = acc1 * SCALE;
    }

    // masked softmax, wave-local (row lives in sc0/sc1)
    float mx = -FLT_MAX;
    #pragma unroll
    for (int c = 0; c < 16; ++c) {
        if (c*128 + sub      <= qrow) mx = fmaxf(mx, sc0[c]);
        if (c*128 + sub + 64 <= qrow) mx = fmaxf(mx, sc1[c]);
    }
    #pragma unroll
    for (int off = 32; off; off >>= 1) mx = fmaxf(mx, __shfl_xor(mx, off, 64));

    float sum = 0.f;
    #pragma unroll
    for (int c = 0; c < 16; ++c) {
        sc0[c] = (c*128 + sub      <= qrow) ? __expf(sc0[c] - mx) : 0.f;
        sc1[c] = (c*128 + sub + 64 <= qrow) ? __expf(sc1[c] - mx) : 0.f;
        sum += sc0[c] + sc1[c];
    }
    #pragma unroll
    for (int off = 32; off; off >>= 1) sum += __shfl_xor(sum, off, 64);
    float inv = 1.f / sum;

    float* arow = attn + (size_t)(bh*NS + rank) * L_;
    #pragma unroll
    for (int c = 0; c < 16; ++c) {
        arow[c*128 + sub]      = sc0[c] * inv;         // coalesced
        arow[c*128 + sub + 64] = sc1[c] * inv;
    }
}

// ---------------------------------------------------------------------------
// K4b: out[bh, qrow_r, :] = attn_row_r @ v for 4 ranks per block.
// Each v float4 is read once and reused for all 4 accumulators
// (weights past each rank's qrow are zeros, so no masking needed).
// ---------------------------------------------------------------------------
__global__ __launch_bounds__(256) void pv_kernel(
    const float* __restrict__ v, const int* __restrict__ idxSel,
    const float* __restrict__ attn, float* __restrict__ out)
{
    __shared__ float wl[4][L_ + 64];    // per-rank weights, j + 4*(j>>7) pad
    __shared__ float4 part[16][16];
    __shared__ int qr4[4];
    int bh = blockIdx.x / 10, grp = blockIdx.x % 10;
    int t = threadIdx.x;
    if (t < 4) qr4[t] = idxSel[bh*NS + grp*4 + t];

    // stage 4 weight rows (coalesced f4 loads)
    #pragma unroll
    for (int it = 0; it < 8; ++it) {
        int f = t + 256*it;             // 0..2047 f4 across 4 rows
        int rr = f >> 9, fi = f & 511;
        const float4* ar = (const float4*)(attn + (size_t)(bh*NS + grp*4 + rr) * L_);
        float4 x = ar[fi];
        int j = 4*fi;
        *((float4*)&wl[rr][j + 4*(j >> 7)]) = x;
    }
    __syncthreads();

    int maxq = max(max(qr4[0], qr4[1]), max(qr4[2], qr4[3]));
    int d4 = t & 15, seg = t >> 4;
    const float4* vb = (const float4*)(v + (size_t)bh * L_ * D_);
    float4 acc[4];
    #pragma unroll
    for (int rr = 0; rr < 4; ++rr) acc[rr] = make_float4(0,0,0,0);

    int jlo = seg*128, jhi = min(jlo + 127, maxq);
    for (int j = jlo; j <= jhi; ++j) {
        float4 x = vb[(size_t)j*16 + d4];          // read once
        int jp = j + 4*(j >> 7);
        #pragma unroll
        for (int rr = 0; rr < 4; ++rr) {
            float wgt = wl[rr][jp];                // 2-way conflict (free)
            acc[rr].x += wgt*x.x; acc[rr].y += wgt*x.y;
            acc[rr].z += wgt*x.z; acc[rr].w += wgt*x.w;
        }
    }

    #pragma unroll
    for (int rr = 0; rr < 4; ++rr) {
        part[seg][d4] = acc[rr];
        __syncthreads();
        float4 a = acc[rr];
        for (int s2 = 8; s2; s2 >>= 1) {
            if (seg < s2) {
                float4 o = part[seg + s2][d4];
                a.x += o.x; a.y += o.y; a.z += o.z; a.w += o.w;
                part[seg][d4] = a;
            }
            __syncthreads();
        }
        if (seg == 0) {
            float4* orow = (float4*)(out + ((size_t)bh * L_ + qr4[rr]) * D_);
            orow[d4] = a;
        }
        __syncthreads();                // before part reuse
    }
}

// ---------------------------------------------------------------------------
extern "C" void kernel_launch(void* const* d_in, const int* in_sizes, int n_in,
                              void* d_out, int out_size, void* d_ws, size_t ws_size,
                              hipStream_t stream) {
    const float* q    = (const float*)d_in[0];
    const float* k    = (const float*)d_in[1];
    const float* v    = (const float*)d_in[2];
    const int*   ridx = (const int*)d_in[3];

    float* out     = (float*)d_out;                    // (B,H,L,D)
    float* attnOut = out + (size_t)BH * L_ * D_;       // (B,H,NS,L)

    float*  measure = (float*)d_ws;                                          // BH*L floats
    int*    idxSel  = (int*)((char*)d_ws + (size_t)BH * L_ * sizeof(float)); // BH*NS ints
    float4* vpart   = (float4*)d_ws;   // aliases measure: only used AFTER topk

    measure_kernel<<<BH * L_ / 4, 256, 0, stream>>>(q, k, ridx, measure);
    topk_kernel   <<<BH,          256, 0, stream>>>(measure, idxSel);
    cumsum_p1     <<<BH * 16,     256, 0, stream>>>(v, vpart);
    cumsum_p2     <<<BH * 16,     256, 0, stream>>>(v, vpart, out);
    scores_kernel <<<BH * 10,     256, 0, stream>>>(q, k, idxSel, attnOut);
    pv_kernel     <<<BH * 10,     256, 0, stream>>>(v, idxSel, attnOut, out);
}

// Round 5
// 331.180 us; speedup vs baseline: 1.1764x; 1.1764x over previous
//
#include <hip/hip_runtime.h>
#include <float.h>
#include <math.h>

#define B_  8
#define H_  8
#define L_  2048
#define D_  64
#define NS  40          // num selected = min(5*ceil(ln(2048)), 2048) = 40
#define BH  (B_*H_)
#define SCALE 0.125f    // d^-0.5

// XCD swizzle: MI355X dispatches block b to XCD (b % 8).  We remap so that
// bh % 8 == b % 8 for every kernel -> all blocks of one bh run on one XCD,
// keeping that bh's k/v/measure/attn slices resident in its 4MB L2.

// ---------------------------------------------------------------------------
// K1: sparsity measure.  One wave per query.  Quarter-wave (16 lanes x f4)
// reads one k row per gather instruction (4 rows / 16 clustered lines per
// instr).  10 passes cover 40 samples.  [R3 scheme - R4's 4-lane split
// regressed: fine-scattered lines + 20% wasted rows]
// ---------------------------------------------------------------------------
__global__ __launch_bounds__(256) void measure_kernel(
    const float* __restrict__ q, const float* __restrict__ k,
    const int* __restrict__ ridx, float* __restrict__ measure)
{
    int wave = threadIdx.x >> 6, lane = threadIdx.x & 63;
    int b = blockIdx.x;
    int xcd = b & 7, s = b >> 3;          // s in 0..4095
    int bh  = xcd + ((s >> 9) << 3);      // 8 bh per XCD, sequential
    int i   = (s & 511) * 4 + wave;       // query row within bh
    int qj  = lane >> 4;                  // quarter id 0..3
    int d4  = lane & 15;                  // float4 index within row

    int rs = ridx[i * NS + (lane < NS ? lane : NS - 1)];

    const float4* kb = (const float4*)(k + (size_t)bh * L_ * D_);
    float4 qq = ((const float4*)(q + ((size_t)bh * L_ + i) * D_))[d4];

    float mx = -FLT_MAX, sm = 0.f;
    #pragma unroll
    for (int p = 0; p < 10; ++p) {
        int j = p * 4 + qj;                      // sample handled by my quarter
        int r = __shfl(rs, j, 64);
        float4 kk = kb[(size_t)r * 16 + d4];     // 16 lanes cover the row
        float pp = qq.x*kk.x + qq.y*kk.y + qq.z*kk.z + qq.w*kk.w;
        pp += __shfl_xor(pp, 1, 64);
        pp += __shfl_xor(pp, 2, 64);
        pp += __shfl_xor(pp, 4, 64);
        pp += __shfl_xor(pp, 8, 64);             // all 16 lanes: dot(q, k[r])
        mx = fmaxf(mx, pp);
        sm += pp;
    }
    // combine the 4 quarters (each holds stats over its 10 samples)
    mx = fmaxf(mx, __shfl_xor(mx, 16, 64));  sm += __shfl_xor(sm, 16, 64);
    mx = fmaxf(mx, __shfl_xor(mx, 32, 64));  sm += __shfl_xor(sm, 32, 64);
    if (lane == 0)
        measure[(size_t)bh * L_ + i] = mx - sm * (1.0f / (float)L_);
}

// ---------------------------------------------------------------------------
// K2: top-NS per (b,h), register-resident.  Ties: lower index (lax.top_k).
// Swizzled so bh%8 == xcd: reads measure from the L2 that produced it.
// ---------------------------------------------------------------------------
__global__ __launch_bounds__(256) void topk_kernel(
    const float* __restrict__ measure, int* __restrict__ idxOut)
{
    __shared__ float wv[4]; __shared__ int wi[4];
    __shared__ float bvS;   __shared__ int biS;
    int b = blockIdx.x;
    int bh = (b & 7) + ((b >> 3) << 3);   // identity, but keeps mapping explicit
    int t = threadIdx.x;
    const float4* m4 = (const float4*)(measure + (size_t)bh * L_);
    float vals[8];
    float4 a = m4[t*2], bb = m4[t*2 + 1];
    vals[0]=a.x; vals[1]=a.y; vals[2]=a.z; vals[3]=a.w;
    vals[4]=bb.x; vals[5]=bb.y; vals[6]=bb.z; vals[7]=bb.w;

    float lv = -FLT_MAX; int li = t*8;
    #pragma unroll
    for (int e = 0; e < 8; ++e) if (vals[e] > lv) { lv = vals[e]; li = t*8 + e; }

    int lane = t & 63, w = t >> 6;
    for (int r = 0; r < NS; ++r) {
        float v = lv; int idx = li;
        #pragma unroll
        for (int off = 32; off; off >>= 1) {
            float ov = __shfl_xor(v, off, 64);
            int   oi = __shfl_xor(idx, off, 64);
            if (ov > v || (ov == v && oi < idx)) { v = ov; idx = oi; }
        }
        if (lane == 0) { wv[w] = v; wi[w] = idx; }
        __syncthreads();
        if (t == 0) {
            float bv = wv[0]; int bi = wi[0];
            #pragma unroll
            for (int ww = 1; ww < 4; ++ww)
                if (wv[ww] > bv || (wv[ww] == bv && wi[ww] < bi)) { bv = wv[ww]; bi = wi[ww]; }
            bvS = bv; biS = bi;
            idxOut[bh * NS + r] = bi;
        }
        __syncthreads();
        int bi = biS;
        if ((bi >> 3) == t) {
            #pragma unroll
            for (int e = 0; e < 8; ++e) if ((bi & 7) == e) vals[e] = -FLT_MAX;
            lv = -FLT_MAX; li = t*8;
            #pragma unroll
            for (int e = 0; e < 8; ++e) if (vals[e] > lv) { lv = vals[e]; li = t*8 + e; }
        }
        __syncthreads();
    }
}

// ---------------------------------------------------------------------------
// K3: cumsum(v) along L, two passes, 1024 blocks each, XCD-swizzled.
// ---------------------------------------------------------------------------
__global__ __launch_bounds__(256) void cumsum_p1(
    const float* __restrict__ v, float4* __restrict__ vpart)
{
    __shared__ float4 part[16][16];
    int b = blockIdx.x;
    int xcd = b & 7, s = b >> 3;          // s in 0..127
    int bh = xcd + ((s >> 4) << 3);
    int c  = s & 15;
    int d4 = threadIdx.x & 15, sub = threadIdx.x >> 4;
    const float4* vb = (const float4*)(v + (size_t)bh * L_ * D_);
    int r0 = c*128 + sub*8;
    float4 acc = make_float4(0,0,0,0);
    #pragma unroll
    for (int r = 0; r < 8; ++r) {
        float4 x = vb[(r0 + r)*16 + d4];
        acc.x += x.x; acc.y += x.y; acc.z += x.z; acc.w += x.w;
    }
    part[sub][d4] = acc;
    __syncthreads();
    if (sub == 0) {
        float4 tot = part[0][d4];
        #pragma unroll
        for (int ss = 1; ss < 16; ++ss) {
            float4 x = part[ss][d4];
            tot.x += x.x; tot.y += x.y; tot.z += x.z; tot.w += x.w;
        }
        vpart[(bh*16 + c)*16 + d4] = tot;
    }
}

__global__ __launch_bounds__(256) void cumsum_p2(
    const float* __restrict__ v, const float4* __restrict__ vpart,
    float* __restrict__ out)
{
    __shared__ float4 part[16][16];
    int b = blockIdx.x;
    int xcd = b & 7, s = b >> 3;
    int bh = xcd + ((s >> 4) << 3);
    int c  = s & 15;
    int d4 = threadIdx.x & 15, sub = threadIdx.x >> 4;
    const float4* vb = (const float4*)(v + (size_t)bh * L_ * D_);
    float4*       ob = (float4*)(out + (size_t)bh * L_ * D_);
    int r0 = c*128 + sub*8;
    float4 acc = make_float4(0,0,0,0);
    #pragma unroll
    for (int r = 0; r < 8; ++r) {
        float4 x = vb[(r0 + r)*16 + d4];
        acc.x += x.x; acc.y += x.y; acc.z += x.z; acc.w += x.w;
    }
    part[sub][d4] = acc;
    float4 run = make_float4(0,0,0,0);
    for (int cc = 0; cc < c; ++cc) {
        float4 x = vpart[(bh*16 + cc)*16 + d4];
        run.x += x.x; run.y += x.y; run.z += x.z; run.w += x.w;
    }
    __syncthreads();
    #pragma unroll
    for (int ss = 0; ss < 16; ++ss) {
        if (ss < sub) {
            float4 x = part[ss][d4];
            run.x += x.x; run.y += x.y; run.z += x.z; run.w += x.w;
        }
    }
    #pragma unroll
    for (int r = 0; r < 8; ++r) {
        float4 x = vb[(r0 + r)*16 + d4];
        run.x += x.x; run.y += x.y; run.z += x.z; run.w += x.w;
        ob[(r0 + r)*16 + d4] = run;
    }
}

// ---------------------------------------------------------------------------
// K4a: scores + softmax fused.  Block = (bh, group of 4 ranks), one wave per
// rank, XCD-swizzled (k slice L2-resident).  Writes normalized weights
// (zeros past qrow).
// ---------------------------------------------------------------------------
__global__ __launch_bounds__(256) void scores_kernel(
    const float* __restrict__ q, const float* __restrict__ k,
    const int* __restrict__ idxSel, float* __restrict__ attn)
{
    __shared__ float4 kbuf[16 * 129];   // [g][j], stride 129 f4
    int b = blockIdx.x;
    int xcd = b & 7, s = b >> 3;          // s in 0..79
    int bh  = xcd + ((s / 10) << 3);
    int grp = s % 10;
    int qi = threadIdx.x >> 6, sub = threadIdx.x & 63;
    int rank = grp*4 + qi;
    int qrow = idxSel[bh*NS + rank];

    const float4* qrp = (const float4*)(q + ((size_t)bh * L_ + qrow) * D_);
    float4 qreg[16];
    #pragma unroll
    for (int g = 0; g < 16; ++g) qreg[g] = qrp[g];    // wave-uniform

    const float4* kb = (const float4*)(k + (size_t)bh * L_ * D_);
    float sc0[16], sc1[16];

    #pragma unroll
    for (int c = 0; c < 16; ++c) {
        __syncthreads();                               // kbuf reuse guard
        int j0 = c * 128;
        #pragma unroll
        for (int it = 0; it < 8; ++it) {               // coalesced stage
            int fi = threadIdx.x + 256*it;
            int g = fi & 15, j = fi >> 4;
            kbuf[g*129 + j] = kb[(size_t)(j0 + j)*16 + g];
        }
        __syncthreads();
        float acc0 = 0.f, acc1 = 0.f;
        #pragma unroll
        for (int g = 0; g < 16; ++g) {
            float4 k0 = kbuf[g*129 + sub];             // dense b128
            float4 k1 = kbuf[g*129 + sub + 64];
            float4 qq = qreg[g];
            acc0 += qq.x*k0.x + qq.y*k0.y + qq.z*k0.z + qq.w*k0.w;
            acc1 += qq.x*k1.x + qq.y*k1.y + qq.z*k1.z + qq.w*k1.w;
        }
        sc0[c] = acc0 * SCALE;
        sc1[c] = acc1 * SCALE;
    }

    // masked softmax, wave-local (row lives in sc0/sc1)
    float mx = -FLT_MAX;
    #pragma unroll
    for (int c = 0; c < 16; ++c) {
        if (c*128 + sub      <= qrow) mx = fmaxf(mx, sc0[c]);
        if (c*128 + sub + 64 <= qrow) mx = fmaxf(mx, sc1[c]);
    }
    #pragma unroll
    for (int off = 32; off; off >>= 1) mx = fmaxf(mx, __shfl_xor(mx, off, 64));

    float sum = 0.f;
    #pragma unroll
    for (int c = 0; c < 16; ++c) {
        sc0[c] = (c*128 + sub      <= qrow) ? __expf(sc0[c] - mx) : 0.f;
        sc1[c] = (c*128 + sub + 64 <= qrow) ? __expf(sc1[c] - mx) : 0.f;
        sum += sc0[c] + sc1[c];
    }
    #pragma unroll
    for (int off = 32; off; off >>= 1) sum += __shfl_xor(sum, off, 64);
    float inv = 1.f / sum;

    float* arow = attn + (size_t)(bh*NS + rank) * L_;
    #pragma unroll
    for (int c = 0; c < 16; ++c) {
        arow[c*128 + sub]      = sc0[c] * inv;         // coalesced
        arow[c*128 + sub + 64] = sc1[c] * inv;
    }
}

// ---------------------------------------------------------------------------
// K4b: out[bh, qrow_r, :] = attn_row_r @ v for 4 ranks per block,
// XCD-swizzled (v + attn slices L2-resident).
// ---------------------------------------------------------------------------
__global__ __launch_bounds__(256) void pv_kernel(
    const float* __restrict__ v, const int* __restrict__ idxSel,
    const float* __restrict__ attn, float* __restrict__ out)
{
    __shared__ float wl[4][L_ + 64];    // per-rank weights, j + 4*(j>>7) pad
    __shared__ float4 part[16][16];
    __shared__ int qr4[4];
    int b = blockIdx.x;
    int xcd = b & 7, s = b >> 3;          // s in 0..79
    int bh  = xcd + ((s / 10) << 3);
    int grp = s % 10;
    int t = threadIdx.x;
    if (t < 4) qr4[t] = idxSel[bh*NS + grp*4 + t];

    // stage 4 weight rows (coalesced f4 loads)
    #pragma unroll
    for (int it = 0; it < 8; ++it) {
        int f = t + 256*it;             // 0..2047 f4 across 4 rows
        int rr = f >> 9, fi = f & 511;
        const float4* ar = (const float4*)(attn + (size_t)(bh*NS + grp*4 + rr) * L_);
        float4 x = ar[fi];
        int j = 4*fi;
        *((float4*)&wl[rr][j + 4*(j >> 7)]) = x;
    }
    __syncthreads();

    int maxq = max(max(qr4[0], qr4[1]), max(qr4[2], qr4[3]));
    int d4 = t & 15, seg = t >> 4;
    const float4* vb = (const float4*)(v + (size_t)bh * L_ * D_);
    float4 acc[4];
    #pragma unroll
    for (int rr = 0; rr < 4; ++rr) acc[rr] = make_float4(0,0,0,0);

    int jlo = seg*128, jhi = min(jlo + 127, maxq);
    for (int j = jlo; j <= jhi; ++j) {
        float4 x = vb[(size_t)j*16 + d4];          // read once
        int jp = j + 4*(j >> 7);
        #pragma unroll
        for (int rr = 0; rr < 4; ++rr) {
            float wgt = wl[rr][jp];                // 2-way conflict (free)
            acc[rr].x += wgt*x.x; acc[rr].y += wgt*x.y;
            acc[rr].z += wgt*x.z; acc[rr].w += wgt*x.w;
        }
    }

    #pragma unroll
    for (int rr = 0; rr < 4; ++rr) {
        part[seg][d4] = acc[rr];
        __syncthreads();
        float4 a = acc[rr];
        for (int s2 = 8; s2; s2 >>= 1) {
            if (seg < s2) {
                float4 o = part[seg + s2][d4];
                a.x += o.x; a.y += o.y; a.z += o.z; a.w += o.w;
                part[seg][d4] = a;
            }
            __syncthreads();
        }
        if (seg == 0) {
            float4* orow = (float4*)(out + ((size_t)bh * L_ + qr4[rr]) * D_);
            orow[d4] = a;
        }
        __syncthreads();                // before part reuse
    }
}

// ---------------------------------------------------------------------------
extern "C" void kernel_launch(void* const* d_in, const int* in_sizes, int n_in,
                              void* d_out, int out_size, void* d_ws, size_t ws_size,
                              hipStream_t stream) {
    const float* q    = (const float*)d_in[0];
    const float* k    = (const float*)d_in[1];
    const float* v    = (const float*)d_in[2];
    const int*   ridx = (const int*)d_in[3];

    float* out     = (float*)d_out;                    // (B,H,L,D)
    float* attnOut = out + (size_t)BH * L_ * D_;       // (B,H,NS,L)

    float*  measure = (float*)d_ws;                                          // BH*L floats
    int*    idxSel  = (int*)((char*)d_ws + (size_t)BH * L_ * sizeof(float)); // BH*NS ints
    float4* vpart   = (float4*)d_ws;   // aliases measure: only used AFTER topk

    measure_kernel<<<BH * L_ / 4, 256, 0, stream>>>(q, k, ridx, measure);
    topk_kernel   <<<BH,          256, 0, stream>>>(measure, idxSel);
    cumsum_p1     <<<BH * 16,     256, 0, stream>>>(v, vpart);
    cumsum_p2     <<<BH * 16,     256, 0, stream>>>(v, vpart, out);
    scores_kernel <<<BH * 10,     256, 0, stream>>>(q, k, idxSel, attnOut);
    pv_kernel     <<<BH * 10,     256, 0, stream>>>(v, idxSel, attnOut, out);
}